// Round 6
// baseline (134.590 us; speedup 1.0000x reference)
//
#include <hip/hip_runtime.h>
#include <hip/hip_cooperative_groups.h>
#include <math.h>

namespace cg = cooperative_groups;

#define BB 4
#define HH 512
#define WW 512
#define HWSZ (HH * WW)

#define GRID 256      // 1 block/CU, co-resident (cooperative)
#define BLKT 512      // 8 waves

// Phase A tiling: 8 cols/block x 64 chunks x 8 rows/chunk
#define ACOLS 8
#define ACH   64
#define AROWS 8
#define BIGR  0x100000            // "no seed" sentinel for min-scans

#define SK(x) ((x) + ((x) >> 5))  // LDS skew (2-way max, free per m136)

// ws layout:
//   [0,    1024)   int flags[256]       (per block: this tile's batch-slice has fg)
//   [1024, 3072)   double partials[256] (one per block)
//   [32768, +4MB)  u32 gpack[BB*HH*WW]  (low16 = g seed=mask, high16 = g seed=~mask)

struct PhaseA {                    // 18.4 KB
    int LN[ACH][ACOLS + 1], FN[ACH][ACOLS + 1];
    int LP[ACH][ACOLS + 1], FP[ACH][ACOLS + 1];
    int BN[ACH][ACOLS + 1], AN[ACH][ACOLS + 1];
    int BP[ACH][ACOLS + 1], AP[ACH][ACOLS + 1];
    int cnt;
};
struct PhaseB {                    // 33.8 KB
    float g2[8][2][SK(511) + 1];   // [wave][n|p][skewed col]
    double wp[8];
};
struct PhaseC { double red[8]; };

// ---------------------------------------------------------------------------
// Single cooperative kernel: Phase A (column EDT via bitmask + shuffle scans)
// -> grid.sync -> Phase B (row lower-envelope, wave-per-row, exact expanding
// ring with early exit) -> grid.sync -> Phase C (block 0 reduces 256 doubles).
// No global atomics, no fences beyond the two grid syncs.
// ---------------------------------------------------------------------------
__global__ __launch_bounds__(BLKT) void boundary_fused_kernel(
    const int* __restrict__ target,
    const float* __restrict__ pred,
    unsigned int* __restrict__ gpack,
    int* __restrict__ flags,
    double* __restrict__ partials,
    float* __restrict__ out)
{
    __shared__ union { PhaseA a; PhaseB bb; PhaseC c; } sh;
    cg::grid_group grid = cg::this_grid();

    int blk = blockIdx.x;          // b*64 + tile
    int tid = threadIdx.x;
    int w = tid >> 6, lane = tid & 63;

    // ============================ Phase A ================================
    {
        int b = blk >> 6;
        int tile = blk & 63;
        int c = tid & (ACOLS - 1);     // column within tile
        int ch = tid >> 3;             // chunk 0..63
        int j = tile * ACOLS + c;
        int r0 = ch * AROWS;

        const int* t = target + b * HWSZ + j;
        unsigned int maskN = 0;        // 8 independent loads -> row bitmask
#pragma unroll
        for (int i = 0; i < AROWS; ++i)
            maskN |= (unsigned int)(t[(r0 + i) * WW] == 1) << i;
        unsigned int maskP = maskN ^ 0xFFu;

        sh.a.LN[ch][c] = maskN ? (r0 + 31 - __builtin_clz(maskN)) : -1;
        sh.a.FN[ch][c] = maskN ? (r0 + __builtin_ctz(maskN))      : BIGR;
        sh.a.LP[ch][c] = maskP ? (r0 + 31 - __builtin_clz(maskP)) : -1;
        sh.a.FP[ch][c] = maskP ? (r0 + __builtin_ctz(maskP))      : BIGR;

        int cnt = __popc(maskN);       // wave reduce, one LDS atomic per wave
#pragma unroll
        for (int off = 32; off > 0; off >>= 1) cnt += __shfl_down(cnt, off, 64);
        if (tid == 0) sh.a.cnt = 0;
        __syncthreads();
        if ((tid & 63) == 0) atomicAdd(&sh.a.cnt, cnt);

        // scans: wave w owns column w; lane = chunk (full 64-wide, 6 steps)
        int iLN = sh.a.LN[lane][w], iLP = sh.a.LP[lane][w];
        int iFN = sh.a.FN[lane][w], iFP = sh.a.FP[lane][w];
#pragma unroll
        for (int d = 1; d < 64; d <<= 1) {          // inclusive fwd max-scan
            int uLN = __shfl_up(iLN, d, 64);
            int uLP = __shfl_up(iLP, d, 64);
            if (lane >= d) { iLN = max(iLN, uLN); iLP = max(iLP, uLP); }
        }
#pragma unroll
        for (int d = 1; d < 64; d <<= 1) {          // inclusive bwd min-scan
            int dFN = __shfl_down(iFN, d, 64);
            int dFP = __shfl_down(iFP, d, 64);
            if (lane + d < 64) { iFN = min(iFN, dFN); iFP = min(iFP, dFP); }
        }
        int bLN = __shfl_up(iLN, 1, 64);   if (lane == 0)  bLN = -1;   // exclusive
        int bLP = __shfl_up(iLP, 1, 64);   if (lane == 0)  bLP = -1;
        int aFN = __shfl_down(iFN, 1, 64); if (lane == 63) aFN = BIGR;
        int aFP = __shfl_down(iFP, 1, 64); if (lane == 63) aFP = BIGR;
        sh.a.BN[lane][w] = bLN; sh.a.BP[lane][w] = bLP;
        sh.a.AN[lane][w] = aFN; sh.a.AP[lane][w] = aFP;
        __syncthreads();

        int befN = sh.a.BN[ch][c], befP = sh.a.BP[ch][c];
        int aftN = sh.a.AN[ch][c], aftP = sh.a.AP[ch][c];
        unsigned int* gp = gpack + b * HWSZ + j;

#pragma unroll
        for (int i = 0; i < AROWS; ++i) {
            int row = r0 + i;
            unsigned int belowN = maskN << (31 - i);   // bit31 = row i
            unsigned int aboveN = maskN >> i;          // bit0  = row i
            unsigned int dfN = belowN ? (unsigned int)__builtin_clz(belowN)
                                      : (befN >= 0 ? (unsigned int)(row - befN) : 0xFFFFu);
            unsigned int dbN = aboveN ? (unsigned int)__builtin_ctz(aboveN)
                                      : (aftN < BIGR ? (unsigned int)(aftN - row) : 0xFFFFu);
            unsigned int gN = dfN < dbN ? dfN : dbN;
            if (gN > 0xFFFFu) gN = 0xFFFFu;

            unsigned int belowP = maskP << (31 - i);
            unsigned int aboveP = maskP >> i;
            unsigned int dfP = belowP ? (unsigned int)__builtin_clz(belowP)
                                      : (befP >= 0 ? (unsigned int)(row - befP) : 0xFFFFu);
            unsigned int dbP = aboveP ? (unsigned int)__builtin_ctz(aboveP)
                                      : (aftP < BIGR ? (unsigned int)(aftP - row) : 0xFFFFu);
            unsigned int gP = dfP < dbP ? dfP : dbP;
            if (gP > 0xFFFFu) gP = 0xFFFFu;

            gp[row * WW] = gN | (gP << 16);
        }

        if (tid == 0) flags[blk] = (sh.a.cnt > 0);
    }

    grid.sync();

    // ============================ Phase B ================================
    {
        int bi = blk * 8 + w;          // global row id 0..2047
        int b = bi >> 9;
        int i = bi & (HH - 1);
        int j0 = 8 * lane;

        // presence guard: 64 tiles per batch, ballot across the wave
        int f = flags[(b << 6) + lane];
        unsigned long long pres = __ballot(f != 0);

        const float* p0 = pred + (b * 2 + 0) * HWSZ + i * WW + j0;
        const float* p1 = pred + (b * 2 + 1) * HWSZ + i * WW + j0;
        float4 a0 = *(const float4*)(p0);      // issued early, consumed late
        float4 a1 = *(const float4*)(p0 + 4);
        float4 c0 = *(const float4*)(p1);
        float4 c1 = *(const float4*)(p1 + 4);

        const uint4* gp4 = (const uint4*)(gpack + b * HWSZ + i * WW);
        uint4 ga = gp4[lane];
        uint4 gb = gp4[lane + 64];

        float* g2n = sh.bb.g2[w][0];   // per-wave private LDS slice
        float* g2p = sh.bb.g2[w][1];
        unsigned int va[4] = {ga.x, ga.y, ga.z, ga.w};
        unsigned int vb[4] = {gb.x, gb.y, gb.z, gb.w};
#pragma unroll
        for (int t = 0; t < 4; ++t) {
            int idx = 4 * lane + t;
            unsigned int gN = va[t] & 0xFFFFu, gP = va[t] >> 16;
            g2n[SK(idx)] = (gN == 0xFFFFu) ? 1e18f : (float)(gN * gN);
            g2p[SK(idx)] = (gP == 0xFFFFu) ? 1e18f : (float)(gP * gP);
            int idx2 = 256 + 4 * lane + t;
            gN = vb[t] & 0xFFFFu; gP = vb[t] >> 16;
            g2n[SK(idx2)] = (gN == 0xFFFFu) ? 1e18f : (float)(gN * gN);
            g2p[SK(idx2)] = (gP == 0xFFFFu) ? 1e18f : (float)(gP * gP);
        }
        // wave-coherent LDS: no barrier needed (per-wave slice, program order)

        float bn[8], bp[8];
#pragma unroll
        for (int jj = 0; jj < 8; ++jj) {
            bn[jj] = g2n[SK(j0 + jj)];
            bp[jj] = g2p[SK(j0 + jj)];
        }
        for (int r = 1; r < WW; ++r) {
            float sq = (float)(r * r);
            float mx = 0.0f;
#pragma unroll
            for (int jj = 0; jj < 8; ++jj) mx = fmaxf(mx, fmaxf(bn[jj], bp[jj]));
            if (sq >= mx) break;       // exact early exit
#pragma unroll
            for (int jj = 0; jj < 8; ++jj) {
                int kl = j0 + jj - r; kl = kl < 0 ? 0 : kl;
                int kr = j0 + jj + r; kr = kr > (WW - 1) ? (WW - 1) : kr;
                int skl = SK(kl), skr = SK(kr);
                bn[jj] = fminf(bn[jj], sq + g2n[skl]);
                bp[jj] = fminf(bp[jj], sq + g2p[skl]);
                bn[jj] = fminf(bn[jj], sq + g2n[skr]);
                bp[jj] = fminf(bp[jj], sq + g2p[skr]);
            }
        }

        float x0[8] = {a0.x, a0.y, a0.z, a0.w, a1.x, a1.y, a1.z, a1.w};
        float x1[8] = {c0.x, c0.y, c0.z, c0.w, c1.x, c1.y, c1.z, c1.w};
        float acc = 0.0f;
#pragma unroll
        for (int jj = 0; jj < 8; ++jj) {
            float dist = sqrtf(bn[jj]) - sqrtf(bp[jj]);            // negEDT - posEDT
            float prob = 1.0f / (1.0f + __expf(x0[jj] - x1[jj]));  // softmax class-1
            acc += prob * dist;
        }
#pragma unroll
        for (int off = 32; off > 0; off >>= 1) acc += __shfl_down(acc, off, 64);
        if (lane == 0) sh.bb.wp[w] = pres ? (double)acc : 0.0;  // 'mask.sum()>0'
        __syncthreads();
        if (tid == 0) {
            double s = 0.0;
#pragma unroll
            for (int q = 0; q < 8; ++q) s += sh.bb.wp[q];
            partials[blk] = s;
        }
    }

    grid.sync();

    // ============================ Phase C ================================
    if (blk == 0) {
        double s = (tid < GRID) ? partials[tid] : 0.0;
#pragma unroll
        for (int off = 32; off > 0; off >>= 1) s += __shfl_down(s, off, 64);
        if (lane == 0) sh.c.red[w] = s;
        __syncthreads();
        if (tid == 0) {
            double tot = 0.0;
#pragma unroll
            for (int q = 0; q < 8; ++q) tot += sh.c.red[q];
            out[0] = (float)(tot * (1.0 / 2097152.0));  // mean over B*C*H*W
        }
    }
}

extern "C" void kernel_launch(void* const* d_in, const int* in_sizes, int n_in,
                              void* d_out, int out_size, void* d_ws, size_t ws_size,
                              hipStream_t stream) {
    const float* pred = (const float*)d_in[0];
    const int* target = (const int*)d_in[1];
    float* out = (float*)d_out;

    char* ws = (char*)d_ws;
    int* flags = (int*)(ws + 0);
    double* partials = (double*)(ws + 1024);
    unsigned int* gpack = (unsigned int*)(ws + 32768);

    void* args[] = {(void*)&target, (void*)&pred, (void*)&gpack,
                    (void*)&flags, (void*)&partials, (void*)&out};
    hipLaunchCooperativeKernel((const void*)boundary_fused_kernel,
                               dim3(GRID), dim3(BLKT), args, 0, stream);
}

// Round 7
// 75.134 us; speedup vs baseline: 1.7913x; 1.7913x over previous
//
#include <hip/hip_runtime.h>
#include <math.h>

#define BB 4
#define HH 512
#define WW 512
#define HWSZ (HH * WW)

// ---- cols tiling: 256 thr = 8 col-PAIRS x 32 chunks, 16 rows/chunk
#define NPAIR 8
#define TCH   32
#define CROWS 16
#define COLS_BLOCKS 128              // 4 batches x 32 tiles (16 cols each)
#define ROWS_BLOCKS (BB * HH)        // 2048
#define BIGR 0x100000                // "no seed" sentinel for min-scans

#define SK(x) ((x) + ((x) >> 5))     // LDS skew (2-way max = free, m136)

// ws layout:
//   [0,    512)    int flags[128]      (per cols-block: tile-slice has fg)
//   [1024, 9216)   float partials[2048](one per row; all written by rows)
//   [32768, +4MB)  u32 gpack[BB*HH*WW] (low16 = g seed=mask, high16 = ~mask)

// ---------------------------------------------------------------------------
// Pass 1: per-column 1D nearest-seed distances for BOTH seeds (mask, ~mask).
// Thread owns a column PAIR: 16 int2 loads (independent, deep ILP) build two
// u16 row-bitmasks; chunk summaries (first/last seed row) to LDS; 16 threads
// serially scan 32 chunk-entries (cheap, ~64 LDS ops); per-row distances via
// clz/ctz on the register masks; output 16 uint2 packed stores (two columns
// per instruction). Presence flag via popc wave-reduce.
// ---------------------------------------------------------------------------
__global__ __launch_bounds__(256) void edt_cols_kernel(
    const int* __restrict__ target,
    unsigned int* __restrict__ gpack,
    int* __restrict__ flags)
{
    int blk = blockIdx.x;            // b*32 + tile
    int b = blk >> 5;
    int tile = blk & 31;
    int tid = threadIdx.x;
    int p = tid & (NPAIR - 1);       // pair index 0..7
    int ch = tid >> 3;               // chunk 0..31
    int j = tile * 16 + 2 * p;       // even column
    int r0 = ch * CROWS;

    const int2* t2 = (const int2*)(target + b * HWSZ + j);

    unsigned int m0 = 0, m1 = 0;     // row bitmasks for cols j, j+1
#pragma unroll
    for (int i = 0; i < CROWS; ++i) {
        int2 v = t2[(r0 + i) * (WW / 2)];
        m0 |= (unsigned int)(v.x == 1) << i;
        m1 |= (unsigned int)(v.y == 1) << i;
    }
    unsigned int q0 = m0 ^ 0xFFFFu, q1 = m1 ^ 0xFFFFu;   // ~mask

    __shared__ int sLN[TCH][17], sFN[TCH][17];   // last/first seed row
    __shared__ int sLP[TCH][17], sFP[TCH][17];
    __shared__ int sBN[TCH][17], sAN[TCH][17];   // before/after prefixes
    __shared__ int sBP[TCH][17], sAP[TCH][17];
    __shared__ int sCnt;

    int c0 = 2 * p, c1 = 2 * p + 1;
    sLN[ch][c0] = m0 ? (r0 + 31 - __builtin_clz(m0)) : -1;
    sFN[ch][c0] = m0 ? (r0 + __builtin_ctz(m0))      : BIGR;
    sLP[ch][c0] = q0 ? (r0 + 31 - __builtin_clz(q0)) : -1;
    sFP[ch][c0] = q0 ? (r0 + __builtin_ctz(q0))      : BIGR;
    sLN[ch][c1] = m1 ? (r0 + 31 - __builtin_clz(m1)) : -1;
    sFN[ch][c1] = m1 ? (r0 + __builtin_ctz(m1))      : BIGR;
    sLP[ch][c1] = q1 ? (r0 + 31 - __builtin_clz(q1)) : -1;
    sFP[ch][c1] = q1 ? (r0 + __builtin_ctz(q1))      : BIGR;

    int cnt = __popc(m0) + __popc(m1);   // wave reduce, one LDS atomic/wave
#pragma unroll
    for (int off = 32; off > 0; off >>= 1) cnt += __shfl_down(cnt, off, 64);
    if (tid == 0) sCnt = 0;
    __syncthreads();
    if ((tid & 63) == 0) atomicAdd(&sCnt, cnt);

    if (tid < 16) {                  // serial per-column chunk scan (32 steps)
        int befN = -1, befP = -1;
        for (int k = 0; k < TCH; ++k) {
            sBN[k][tid] = befN; sBP[k][tid] = befP;
            int ln = sLN[k][tid], lp = sLP[k][tid];
            if (ln >= 0) befN = ln;
            if (lp >= 0) befP = lp;
        }
        int aftN = BIGR, aftP = BIGR;
        for (int k = TCH - 1; k >= 0; --k) {
            sAN[k][tid] = aftN; sAP[k][tid] = aftP;
            int fn = sFN[k][tid], fp = sFP[k][tid];
            if (fn < BIGR) aftN = fn;
            if (fp < BIGR) aftP = fp;
        }
    }
    __syncthreads();

    int bN0 = sBN[ch][c0], bP0 = sBP[ch][c0], aN0 = sAN[ch][c0], aP0 = sAP[ch][c0];
    int bN1 = sBN[ch][c1], bP1 = sBP[ch][c1], aN1 = sAN[ch][c1], aP1 = sAP[ch][c1];
    uint2* gp2 = (uint2*)(gpack + b * HWSZ + j);

#pragma unroll
    for (int i = 0; i < CROWS; ++i) {
        int row = r0 + i;
        uint2 outv;
        {   // column j
            unsigned int below = m0 << (31 - i), above = m0 >> i;
            unsigned int df = below ? (unsigned int)__builtin_clz(below)
                                    : (bN0 >= 0 ? (unsigned int)(row - bN0) : 0xFFFFu);
            unsigned int db = above ? (unsigned int)__builtin_ctz(above)
                                    : (aN0 < BIGR ? (unsigned int)(aN0 - row) : 0xFFFFu);
            unsigned int gN = df < db ? df : db; if (gN > 0xFFFFu) gN = 0xFFFFu;
            below = q0 << (31 - i); above = q0 >> i;
            df = below ? (unsigned int)__builtin_clz(below)
                       : (bP0 >= 0 ? (unsigned int)(row - bP0) : 0xFFFFu);
            db = above ? (unsigned int)__builtin_ctz(above)
                       : (aP0 < BIGR ? (unsigned int)(aP0 - row) : 0xFFFFu);
            unsigned int gP = df < db ? df : db; if (gP > 0xFFFFu) gP = 0xFFFFu;
            outv.x = gN | (gP << 16);
        }
        {   // column j+1
            unsigned int below = m1 << (31 - i), above = m1 >> i;
            unsigned int df = below ? (unsigned int)__builtin_clz(below)
                                    : (bN1 >= 0 ? (unsigned int)(row - bN1) : 0xFFFFu);
            unsigned int db = above ? (unsigned int)__builtin_ctz(above)
                                    : (aN1 < BIGR ? (unsigned int)(aN1 - row) : 0xFFFFu);
            unsigned int gN = df < db ? df : db; if (gN > 0xFFFFu) gN = 0xFFFFu;
            below = q1 << (31 - i); above = q1 >> i;
            df = below ? (unsigned int)__builtin_clz(below)
                       : (bP1 >= 0 ? (unsigned int)(row - bP1) : 0xFFFFu);
            db = above ? (unsigned int)__builtin_ctz(above)
                       : (aP1 < BIGR ? (unsigned int)(aP1 - row) : 0xFFFFu);
            unsigned int gP = df < db ? df : db; if (gP > 0xFFFFu) gP = 0xFFFFu;
            outv.y = gN | (gP << 16);
        }
        gp2[row * (WW / 2)] = outv;
    }

    if (tid == 0) flags[blk] = (sCnt > 0);
}

// ---------------------------------------------------------------------------
// Pass 2: one WAVE per image row (R4-proven). Lane k owns columns 8k..8k+7.
// Staging: 2x uint4 gpack + 4x float4 pred. Exact expanding-ring search
// (early exit when r^2 >= all 16 running bests; clamped edge indices only add
// over-estimates -> min stays exact). dmap = sqrt(d2n)-sqrt(d2p) weighted by
// sigmoid(x1-x0). 6-shuffle reduce, one f32 store per row. No atomics/flags.
// ---------------------------------------------------------------------------
__global__ __launch_bounds__(64) void edt_rows_kernel(
    const unsigned int* __restrict__ gpack,
    const float* __restrict__ pred,
    float* __restrict__ partials)
{
    __shared__ float g2n[SK(511) + 1];
    __shared__ float g2p[SK(511) + 1];

    int bi = blockIdx.x;            // b*HH + i
    int b = bi >> 9;
    int i = bi & (HH - 1);
    int k = threadIdx.x;            // lane 0..63
    int j0 = 8 * k;

    const float* p0 = pred + (b * 2 + 0) * HWSZ + i * WW + j0;
    const float* p1 = pred + (b * 2 + 1) * HWSZ + i * WW + j0;
    float4 a0 = *(const float4*)(p0);       // issued early, consumed late
    float4 a1 = *(const float4*)(p0 + 4);
    float4 c0 = *(const float4*)(p1);
    float4 c1 = *(const float4*)(p1 + 4);

    const uint4* gp4 = (const uint4*)(gpack + b * HWSZ + i * WW);
    uint4 ga = gp4[k];
    uint4 gb = gp4[k + 64];

    unsigned int va[4] = {ga.x, ga.y, ga.z, ga.w};
    unsigned int vb[4] = {gb.x, gb.y, gb.z, gb.w};
#pragma unroll
    for (int t = 0; t < 4; ++t) {
        int idx = 4 * k + t;
        unsigned int gN = va[t] & 0xFFFFu, gP = va[t] >> 16;
        g2n[SK(idx)] = (gN == 0xFFFFu) ? 1e18f : (float)(gN * gN);
        g2p[SK(idx)] = (gP == 0xFFFFu) ? 1e18f : (float)(gP * gP);
        int idx2 = 256 + 4 * k + t;
        gN = vb[t] & 0xFFFFu; gP = vb[t] >> 16;
        g2n[SK(idx2)] = (gN == 0xFFFFu) ? 1e18f : (float)(gN * gN);
        g2p[SK(idx2)] = (gP == 0xFFFFu) ? 1e18f : (float)(gP * gP);
    }
    __syncthreads();

    float bn[8], bp[8];
#pragma unroll
    for (int jj = 0; jj < 8; ++jj) {
        bn[jj] = g2n[SK(j0 + jj)];
        bp[jj] = g2p[SK(j0 + jj)];
    }
    for (int r = 1; r < WW; ++r) {
        float sq = (float)(r * r);
        float mx = 0.0f;
#pragma unroll
        for (int jj = 0; jj < 8; ++jj) mx = fmaxf(mx, fmaxf(bn[jj], bp[jj]));
        if (sq >= mx) break;        // exact early exit
#pragma unroll
        for (int jj = 0; jj < 8; ++jj) {
            int kl = j0 + jj - r; kl = kl < 0 ? 0 : kl;
            int kr = j0 + jj + r; kr = kr > (WW - 1) ? (WW - 1) : kr;
            int skl = SK(kl), skr = SK(kr);
            bn[jj] = fminf(bn[jj], sq + g2n[skl]);
            bp[jj] = fminf(bp[jj], sq + g2p[skl]);
            bn[jj] = fminf(bn[jj], sq + g2n[skr]);
            bp[jj] = fminf(bp[jj], sq + g2p[skr]);
        }
    }

    float x0[8] = {a0.x, a0.y, a0.z, a0.w, a1.x, a1.y, a1.z, a1.w};
    float x1[8] = {c0.x, c0.y, c0.z, c0.w, c1.x, c1.y, c1.z, c1.w};
    float acc = 0.0f;
#pragma unroll
    for (int jj = 0; jj < 8; ++jj) {
        float dist = sqrtf(bn[jj]) - sqrtf(bp[jj]);            // negEDT - posEDT
        float prob = 1.0f / (1.0f + __expf(x0[jj] - x1[jj]));  // softmax class-1
        acc += prob * dist;
    }
#pragma unroll
    for (int off = 32; off > 0; off >>= 1) acc += __shfl_down(acc, off, 64);
    if (k == 0) partials[bi] = acc;
}

// ---------------------------------------------------------------------------
// Pass 3: single wave. 8x float4 partial loads per lane, per-batch presence
// guard via 4 ballots over the 32 cols-block flags, double shuffle-reduce.
// ---------------------------------------------------------------------------
__global__ __launch_bounds__(64) void finalize_kernel(
    const int* __restrict__ flags,
    const float* __restrict__ partials,
    float* __restrict__ out)
{
    int k = threadIdx.x;

    double presd[BB];
#pragma unroll
    for (int b = 0; b < BB; ++b) {
        int f = (k < 32) ? flags[b * 32 + k] : 0;
        presd[b] = (__ballot(f != 0) != 0ULL) ? 1.0 : 0.0;  // 'mask.sum()>0'
    }

    const float4* p4 = (const float4*)partials;
    double s = 0.0;
#pragma unroll
    for (int t = 0; t < 8; ++t) {
        int v4 = k + 64 * t;                 // float4 index 0..511
        float4 v = p4[v4];
        double g = presd[v4 >> 7];           // batch = (4*v4)>>9
        s += g * ((double)v.x + (double)v.y + (double)v.z + (double)v.w);
    }
#pragma unroll
    for (int off = 32; off > 0; off >>= 1) s += __shfl_down(s, off, 64);
    if (k == 0)
        out[0] = (float)(s * (1.0 / 2097152.0));   // mean over B*C*H*W
}

extern "C" void kernel_launch(void* const* d_in, const int* in_sizes, int n_in,
                              void* d_out, int out_size, void* d_ws, size_t ws_size,
                              hipStream_t stream) {
    const float* pred = (const float*)d_in[0];
    const int* target = (const int*)d_in[1];
    float* out = (float*)d_out;

    char* ws = (char*)d_ws;
    int* flags = (int*)(ws + 0);
    float* partials = (float*)(ws + 1024);
    unsigned int* gpack = (unsigned int*)(ws + 32768);

    edt_cols_kernel<<<COLS_BLOCKS, 256, 0, stream>>>(target, gpack, flags);
    edt_rows_kernel<<<ROWS_BLOCKS, 64, 0, stream>>>(gpack, pred, partials);
    finalize_kernel<<<1, 64, 0, stream>>>(flags, partials, out);
}

// Round 8
// 73.320 us; speedup vs baseline: 1.8357x; 1.0247x over previous
//
#include <hip/hip_runtime.h>
#include <math.h>

#define BB 4
#define HH 512
#define WW 512
#define HWSZ (HH * WW)

// ---- cols tiling: 256 thr = 8 col-PAIRS x 32 chunks, 16 rows/chunk
#define NPAIR 8
#define TCH   32
#define CROWS 16
#define COLS_BLOCKS 128              // 4 batches x 32 tiles (16 cols each)
#define ROWS_BLOCKS (BB * HH)        // 2048
#define BIGR 0x100000                // "no seed" sentinel for min-scans

#define SK(x) ((x) + ((x) >> 5))     // LDS skew: 64 lanes -> 32 banks 2-way (free)

// ws layout:
//   [0,    512)    int flags[128]      (per cols-block: tile-slice has fg)
//   [1024, 9216)   float partials[2048](one per row; all written by rows)
//   [32768, +4MB)  u32 gpack[BB*HH*WW] (low16 = g seed=mask, high16 = ~mask)

// ---------------------------------------------------------------------------
// Pass 1 (unchanged from R7): per-column 1D nearest-seed distances for BOTH
// seeds. Thread owns a column PAIR: 16 int2 loads build two u16 row-bitmasks;
// chunk summaries to LDS; 16-thread serial chunk scan; per-row distances via
// clz/ctz; 16 uint2 packed stores. Presence flag via popc wave-reduce.
// ---------------------------------------------------------------------------
__global__ __launch_bounds__(256) void edt_cols_kernel(
    const int* __restrict__ target,
    unsigned int* __restrict__ gpack,
    int* __restrict__ flags)
{
    int blk = blockIdx.x;            // b*32 + tile
    int b = blk >> 5;
    int tile = blk & 31;
    int tid = threadIdx.x;
    int p = tid & (NPAIR - 1);       // pair index 0..7
    int ch = tid >> 3;               // chunk 0..31
    int j = tile * 16 + 2 * p;       // even column
    int r0 = ch * CROWS;

    const int2* t2 = (const int2*)(target + b * HWSZ + j);

    unsigned int m0 = 0, m1 = 0;     // row bitmasks for cols j, j+1
#pragma unroll
    for (int i = 0; i < CROWS; ++i) {
        int2 v = t2[(r0 + i) * (WW / 2)];
        m0 |= (unsigned int)(v.x == 1) << i;
        m1 |= (unsigned int)(v.y == 1) << i;
    }
    unsigned int q0 = m0 ^ 0xFFFFu, q1 = m1 ^ 0xFFFFu;   // ~mask

    __shared__ int sLN[TCH][17], sFN[TCH][17];   // last/first seed row
    __shared__ int sLP[TCH][17], sFP[TCH][17];
    __shared__ int sBN[TCH][17], sAN[TCH][17];   // before/after prefixes
    __shared__ int sBP[TCH][17], sAP[TCH][17];
    __shared__ int sCnt;

    int c0 = 2 * p, c1 = 2 * p + 1;
    sLN[ch][c0] = m0 ? (r0 + 31 - __builtin_clz(m0)) : -1;
    sFN[ch][c0] = m0 ? (r0 + __builtin_ctz(m0))      : BIGR;
    sLP[ch][c0] = q0 ? (r0 + 31 - __builtin_clz(q0)) : -1;
    sFP[ch][c0] = q0 ? (r0 + __builtin_ctz(q0))      : BIGR;
    sLN[ch][c1] = m1 ? (r0 + 31 - __builtin_clz(m1)) : -1;
    sFN[ch][c1] = m1 ? (r0 + __builtin_ctz(m1))      : BIGR;
    sLP[ch][c1] = q1 ? (r0 + 31 - __builtin_clz(q1)) : -1;
    sFP[ch][c1] = q1 ? (r0 + __builtin_ctz(q1))      : BIGR;

    int cnt = __popc(m0) + __popc(m1);   // wave reduce, one LDS atomic/wave
#pragma unroll
    for (int off = 32; off > 0; off >>= 1) cnt += __shfl_down(cnt, off, 64);
    if (tid == 0) sCnt = 0;
    __syncthreads();
    if ((tid & 63) == 0) atomicAdd(&sCnt, cnt);

    if (tid < 16) {                  // serial per-column chunk scan (32 steps)
        int befN = -1, befP = -1;
        for (int k = 0; k < TCH; ++k) {
            sBN[k][tid] = befN; sBP[k][tid] = befP;
            int ln = sLN[k][tid], lp = sLP[k][tid];
            if (ln >= 0) befN = ln;
            if (lp >= 0) befP = lp;
        }
        int aftN = BIGR, aftP = BIGR;
        for (int k = TCH - 1; k >= 0; --k) {
            sAN[k][tid] = aftN; sAP[k][tid] = aftP;
            int fn = sFN[k][tid], fp = sFP[k][tid];
            if (fn < BIGR) aftN = fn;
            if (fp < BIGR) aftP = fp;
        }
    }
    __syncthreads();

    int bN0 = sBN[ch][c0], bP0 = sBP[ch][c0], aN0 = sAN[ch][c0], aP0 = sAP[ch][c0];
    int bN1 = sBN[ch][c1], bP1 = sBP[ch][c1], aN1 = sAN[ch][c1], aP1 = sAP[ch][c1];
    uint2* gp2 = (uint2*)(gpack + b * HWSZ + j);

#pragma unroll
    for (int i = 0; i < CROWS; ++i) {
        int row = r0 + i;
        uint2 outv;
        {   // column j
            unsigned int below = m0 << (31 - i), above = m0 >> i;
            unsigned int df = below ? (unsigned int)__builtin_clz(below)
                                    : (bN0 >= 0 ? (unsigned int)(row - bN0) : 0xFFFFu);
            unsigned int db = above ? (unsigned int)__builtin_ctz(above)
                                    : (aN0 < BIGR ? (unsigned int)(aN0 - row) : 0xFFFFu);
            unsigned int gN = df < db ? df : db; if (gN > 0xFFFFu) gN = 0xFFFFu;
            below = q0 << (31 - i); above = q0 >> i;
            df = below ? (unsigned int)__builtin_clz(below)
                       : (bP0 >= 0 ? (unsigned int)(row - bP0) : 0xFFFFu);
            db = above ? (unsigned int)__builtin_ctz(above)
                       : (aP0 < BIGR ? (unsigned int)(aP0 - row) : 0xFFFFu);
            unsigned int gP = df < db ? df : db; if (gP > 0xFFFFu) gP = 0xFFFFu;
            outv.x = gN | (gP << 16);
        }
        {   // column j+1
            unsigned int below = m1 << (31 - i), above = m1 >> i;
            unsigned int df = below ? (unsigned int)__builtin_clz(below)
                                    : (bN1 >= 0 ? (unsigned int)(row - bN1) : 0xFFFFu);
            unsigned int db = above ? (unsigned int)__builtin_ctz(above)
                                    : (aN1 < BIGR ? (unsigned int)(aN1 - row) : 0xFFFFu);
            unsigned int gN = df < db ? df : db; if (gN > 0xFFFFu) gN = 0xFFFFu;
            below = q1 << (31 - i); above = q1 >> i;
            df = below ? (unsigned int)__builtin_clz(below)
                       : (bP1 >= 0 ? (unsigned int)(row - bP1) : 0xFFFFu);
            db = above ? (unsigned int)__builtin_ctz(above)
                       : (aP1 < BIGR ? (unsigned int)(aP1 - row) : 0xFFFFu);
            unsigned int gP = df < db ? df : db; if (gP > 0xFFFFu) gP = 0xFFFFu;
            outv.y = gN | (gP << 16);
        }
        gp2[row * (WW / 2)] = outv;
    }

    if (tid == 0) flags[blk] = (sCnt > 0);
}

// ---------------------------------------------------------------------------
// Pass 2: one WAVE per image row, with SIGN-SELECTION: at every pixel exactly
// one of {neg_dist, pos_dist} is zero (fg pixel -> g2n[j]==0 -> neg=0; bg ->
// pos=0), so only ONE map needs the ring search per column. sel = fg?g2p:g2n,
// dmap contribution = (fg ? -1 : +1) * sqrt(bsel). Bit-identical to computing
// both (the skipped search's result is exactly 0). Halves LDS reads & fmins
// in the inner loop. Clamped edge indices only add over-estimates -> exact.
// ---------------------------------------------------------------------------
__global__ __launch_bounds__(64) void edt_rows_kernel(
    const unsigned int* __restrict__ gpack,
    const float* __restrict__ pred,
    float* __restrict__ partials)
{
    __shared__ float g2n[SK(511) + 1];
    __shared__ float g2p[SK(511) + 1];

    int bi = blockIdx.x;            // b*HH + i
    int b = bi >> 9;
    int i = bi & (HH - 1);
    int k = threadIdx.x;            // lane 0..63
    int j0 = 8 * k;

    const float* p0 = pred + (b * 2 + 0) * HWSZ + i * WW + j0;
    const float* p1 = pred + (b * 2 + 1) * HWSZ + i * WW + j0;
    float4 a0 = *(const float4*)(p0);       // issued early, consumed late
    float4 a1 = *(const float4*)(p0 + 4);
    float4 c0 = *(const float4*)(p1);
    float4 c1 = *(const float4*)(p1 + 4);

    const uint4* gp4 = (const uint4*)(gpack + b * HWSZ + i * WW);
    uint4 ga = gp4[k];
    uint4 gb = gp4[k + 64];

    unsigned int va[4] = {ga.x, ga.y, ga.z, ga.w};
    unsigned int vb[4] = {gb.x, gb.y, gb.z, gb.w};
#pragma unroll
    for (int t = 0; t < 4; ++t) {
        int idx = 4 * k + t;
        unsigned int gN = va[t] & 0xFFFFu, gP = va[t] >> 16;
        g2n[SK(idx)] = (gN == 0xFFFFu) ? 1e18f : (float)(gN * gN);
        g2p[SK(idx)] = (gP == 0xFFFFu) ? 1e18f : (float)(gP * gP);
        int idx2 = 256 + 4 * k + t;
        gN = vb[t] & 0xFFFFu; gP = vb[t] >> 16;
        g2n[SK(idx2)] = (gN == 0xFFFFu) ? 1e18f : (float)(gN * gN);
        g2p[SK(idx2)] = (gP == 0xFFFFu) ? 1e18f : (float)(gP * gP);
    }
    __syncthreads();

    // per-column map selection: fg <=> g2n[j]==0 (own column distance zero)
    const float* sel[8];
    float bs[8], sgn[8];
#pragma unroll
    for (int jj = 0; jj < 8; ++jj) {
        float on = g2n[SK(j0 + jj)];
        float op = g2p[SK(j0 + jj)];
        bool fg = (on == 0.0f);
        sel[jj] = fg ? g2p : g2n;
        bs[jj]  = fg ? op : on;
        sgn[jj] = fg ? -1.0f : 1.0f;   // dmap = neg - pos
    }
    for (int r = 1; r < WW; ++r) {
        float sq = (float)(r * r);
        float mx = 0.0f;
#pragma unroll
        for (int jj = 0; jj < 8; ++jj) mx = fmaxf(mx, bs[jj]);
        if (sq >= mx) break;        // exact early exit
#pragma unroll
        for (int jj = 0; jj < 8; ++jj) {
            int kl = j0 + jj - r; kl = kl < 0 ? 0 : kl;
            int kr = j0 + jj + r; kr = kr > (WW - 1) ? (WW - 1) : kr;
            bs[jj] = fminf(bs[jj], sq + sel[jj][SK(kl)]);
            bs[jj] = fminf(bs[jj], sq + sel[jj][SK(kr)]);
        }
    }

    float x0[8] = {a0.x, a0.y, a0.z, a0.w, a1.x, a1.y, a1.z, a1.w};
    float x1[8] = {c0.x, c0.y, c0.z, c0.w, c1.x, c1.y, c1.z, c1.w};
    float acc = 0.0f;
#pragma unroll
    for (int jj = 0; jj < 8; ++jj) {
        float dist = sgn[jj] * sqrtf(bs[jj]);                  // negEDT - posEDT
        float prob = 1.0f / (1.0f + __expf(x0[jj] - x1[jj]));  // softmax class-1
        acc += prob * dist;
    }
#pragma unroll
    for (int off = 32; off > 0; off >>= 1) acc += __shfl_down(acc, off, 64);
    if (k == 0) partials[bi] = acc;
}

// ---------------------------------------------------------------------------
// Pass 3 (unchanged): single wave. 8x float4 partial loads per lane, per-batch
// presence guard via 4 ballots over the 32 cols-block flags, double reduce.
// ---------------------------------------------------------------------------
__global__ __launch_bounds__(64) void finalize_kernel(
    const int* __restrict__ flags,
    const float* __restrict__ partials,
    float* __restrict__ out)
{
    int k = threadIdx.x;

    double presd[BB];
#pragma unroll
    for (int b = 0; b < BB; ++b) {
        int f = (k < 32) ? flags[b * 32 + k] : 0;
        presd[b] = (__ballot(f != 0) != 0ULL) ? 1.0 : 0.0;  // 'mask.sum()>0'
    }

    const float4* p4 = (const float4*)partials;
    double s = 0.0;
#pragma unroll
    for (int t = 0; t < 8; ++t) {
        int v4 = k + 64 * t;                 // float4 index 0..511
        float4 v = p4[v4];
        double g = presd[v4 >> 7];           // batch = (4*v4)>>9
        s += g * ((double)v.x + (double)v.y + (double)v.z + (double)v.w);
    }
#pragma unroll
    for (int off = 32; off > 0; off >>= 1) s += __shfl_down(s, off, 64);
    if (k == 0)
        out[0] = (float)(s * (1.0 / 2097152.0));   // mean over B*C*H*W
}

extern "C" void kernel_launch(void* const* d_in, const int* in_sizes, int n_in,
                              void* d_out, int out_size, void* d_ws, size_t ws_size,
                              hipStream_t stream) {
    const float* pred = (const float*)d_in[0];
    const int* target = (const int*)d_in[1];
    float* out = (float*)d_out;

    char* ws = (char*)d_ws;
    int* flags = (int*)(ws + 0);
    float* partials = (float*)(ws + 1024);
    unsigned int* gpack = (unsigned int*)(ws + 32768);

    edt_cols_kernel<<<COLS_BLOCKS, 256, 0, stream>>>(target, gpack, flags);
    edt_rows_kernel<<<ROWS_BLOCKS, 64, 0, stream>>>(gpack, pred, partials);
    finalize_kernel<<<1, 64, 0, stream>>>(flags, partials, out);
}

// Round 9
// 72.959 us; speedup vs baseline: 1.8447x; 1.0049x over previous
//
#include <hip/hip_runtime.h>
#include <math.h>

#define BB 4
#define HH 512
#define WW 512
#define HWSZ (HH * WW)
#define ROWS_BLOCKS 256              // 4 batches x 64 row-groups (8 rows each)

#define SK(x) ((x) + ((x) >> 5))     // LDS skew: 64 lanes -> 32 banks 2-way (free)

// ws layout:
//   [0,    512)    int flags[128]       (per pack-block: batch-slice has fg)
//   [1024, 9216)   float partials[2048] (one per row; all written by rows)
//   [32768, +128K) u32 cw[BB][16][512]  (bit i of cw[b][w][col] = mask at row 32w+i)

// ---------------------------------------------------------------------------
// Pass 1: bit-pack the target mask into column words. Thread (b,w,col) reads
// 32 ints down a column (independent loads, lane-consecutive cols = coalesced
// 256B lines) -> one u32. Presence flag per block via popc wave-reduce
// (layout: 32 blocks per batch, matching finalize's ballot).
// ---------------------------------------------------------------------------
__global__ __launch_bounds__(256) void pack_kernel(
    const int* __restrict__ target,
    unsigned int* __restrict__ cw,
    int* __restrict__ flags)
{
    __shared__ int sCnt;
    int gid = blockIdx.x * 256 + threadIdx.x;   // 0..32767
    int b = gid >> 13;
    int rem = gid & 8191;
    int w = rem >> 9;                // word-row 0..15
    int col = rem & 511;

    const int* t = target + b * HWSZ + (w << 5) * WW + col;
    unsigned int word = 0;
#pragma unroll
    for (int i = 0; i < 32; ++i)
        word |= (unsigned int)(t[i * WW] == 1) << i;
    cw[gid] = word;

    int cnt = __popc(word);
#pragma unroll
    for (int off = 32; off > 0; off >>= 1) cnt += __shfl_down(cnt, off, 64);
    if (threadIdx.x == 0) sCnt = 0;
    __syncthreads();
    if ((threadIdx.x & 63) == 0) atomicAdd(&sCnt, cnt);
    __syncthreads();
    if (threadIdx.x == 0) flags[blockIdx.x] = (sCnt > 0);
}

// ---------------------------------------------------------------------------
// Pass 2: 8 rows per block (one per wave). Stage A: load the batch's full
// 32 KB column-word mask into LDS. Stage B: exact per-(row,col) column
// distances gN,gP via clz/ctz on the own word + outward word loop (first
// word hits on dense data; loop keeps worst-case exact). Build per-wave
// g2n/g2p rows in LDS (stride-64 cols -> conflict-free). Stage C: R8's
// sign-select expanding-ring search (exactly one of neg/pos dist is zero
// per pixel -> search one map, emit +/-sqrt; clamped edges over-estimate
// only -> exact), sigmoid weighting, 6-shuffle reduce, one f32 per row.
// ---------------------------------------------------------------------------
__global__ __launch_bounds__(512) void rows_kernel(
    const unsigned int* __restrict__ cw,
    const float* __restrict__ pred,
    float* __restrict__ partials)
{
    __shared__ unsigned int sW[16 * 512];                 // 32 KB
    __shared__ float g2n[8][SK(511) + 1], g2p[8][SK(511) + 1];  // ~33.8 KB

    int blk = blockIdx.x;
    int b = blk >> 6;
    int g = blk & 63;                // row group
    int tid = threadIdx.x;
    int w = tid >> 6, lane = tid & 63;
    int row = 8 * g + w;             // this wave's image row
    int j0 = 8 * lane;               // this lane's ring-search columns

    // pred loads issued first (consumed in stage C)
    const float* p0 = pred + (b * 2 + 0) * HWSZ + row * WW + j0;
    const float* p1 = pred + (b * 2 + 1) * HWSZ + row * WW + j0;
    float4 a0 = *(const float4*)(p0);
    float4 a1 = *(const float4*)(p0 + 4);
    float4 c0 = *(const float4*)(p1);
    float4 c1 = *(const float4*)(p1 + 4);

    // ---- Stage A: batch mask -> LDS (coalesced, 16 words/thread)
    const unsigned int* cwb = cw + b * 8192;
#pragma unroll
    for (int t = 0; t < 16; ++t)
        sW[tid + 512 * t] = cwb[tid + 512 * t];
    __syncthreads();

    // ---- Stage B: build this row's g2n/g2p (lane covers cols lane+64t)
    int wr = row >> 5, bit = row & 31;
    float* G2N = g2n[w];
    float* G2P = g2p[w];
    unsigned int loMask = 0xFFFFFFFFu >> (31 - bit);   // bits 0..bit
    unsigned int hiMask = 0xFFFFFFFFu << bit;          // bits bit..31
#pragma unroll
    for (int t = 0; t < 8; ++t) {
        int col = lane + (t << 6);
        unsigned int Wr = sW[(wr << 9) + col];
        // --- N map (seed = mask)
        int dUp, dDn;
        unsigned int m = Wr & loMask;
        if (m) dUp = bit - (31 - __builtin_clz(m));
        else {
            dUp = 0x7FFFFFFF;
            for (int q = wr - 1; q >= 0; --q) {
                unsigned int W = sW[(q << 9) + col];
                if (W) { dUp = row - ((q << 5) + 31 - __builtin_clz(W)); break; }
            }
        }
        m = Wr & hiMask;
        if (m) dDn = __builtin_ctz(m) - bit;
        else {
            dDn = 0x7FFFFFFF;
            for (int q = wr + 1; q < 16; ++q) {
                unsigned int W = sW[(q << 9) + col];
                if (W) { dDn = (q << 5) + __builtin_ctz(W) - row; break; }
            }
        }
        int gN = min(dUp, dDn);
        G2N[SK(col)] = (gN > 511) ? 1e18f : (float)(gN * gN);
        // --- P map (seed = ~mask)
        unsigned int Vr = ~Wr;
        m = Vr & loMask;
        if (m) dUp = bit - (31 - __builtin_clz(m));
        else {
            dUp = 0x7FFFFFFF;
            for (int q = wr - 1; q >= 0; --q) {
                unsigned int W = ~sW[(q << 9) + col];
                if (W) { dUp = row - ((q << 5) + 31 - __builtin_clz(W)); break; }
            }
        }
        m = Vr & hiMask;
        if (m) dDn = __builtin_ctz(m) - bit;
        else {
            dDn = 0x7FFFFFFF;
            for (int q = wr + 1; q < 16; ++q) {
                unsigned int W = ~sW[(q << 9) + col];
                if (W) { dDn = (q << 5) + __builtin_ctz(W) - row; break; }
            }
        }
        int gP = min(dUp, dDn);
        G2P[SK(col)] = (gP > 511) ? 1e18f : (float)(gP * gP);
    }
    // G2N/G2P are wave-private and wave-coherent: no barrier needed.

    // ---- Stage C: sign-select ring search (R8-proven exact)
    const float* sel[8];
    float bs[8], sgn[8];
#pragma unroll
    for (int jj = 0; jj < 8; ++jj) {
        float on = G2N[SK(j0 + jj)];
        float op = G2P[SK(j0 + jj)];
        bool fg = (on == 0.0f);      // fg pixel -> neg_dist = 0, search pos
        sel[jj] = fg ? G2P : G2N;
        bs[jj]  = fg ? op : on;
        sgn[jj] = fg ? -1.0f : 1.0f; // dmap = neg - pos
    }
    for (int r = 1; r < WW; ++r) {
        float sq = (float)(r * r);
        float mx = 0.0f;
#pragma unroll
        for (int jj = 0; jj < 8; ++jj) mx = fmaxf(mx, bs[jj]);
        if (sq >= mx) break;         // exact early exit
#pragma unroll
        for (int jj = 0; jj < 8; ++jj) {
            int kl = j0 + jj - r; kl = kl < 0 ? 0 : kl;
            int kr = j0 + jj + r; kr = kr > (WW - 1) ? (WW - 1) : kr;
            bs[jj] = fminf(bs[jj], sq + sel[jj][SK(kl)]);
            bs[jj] = fminf(bs[jj], sq + sel[jj][SK(kr)]);
        }
    }

    float x0[8] = {a0.x, a0.y, a0.z, a0.w, a1.x, a1.y, a1.z, a1.w};
    float x1[8] = {c0.x, c0.y, c0.z, c0.w, c1.x, c1.y, c1.z, c1.w};
    float acc = 0.0f;
#pragma unroll
    for (int jj = 0; jj < 8; ++jj) {
        float dist = sgn[jj] * sqrtf(bs[jj]);                  // negEDT - posEDT
        float prob = 1.0f / (1.0f + __expf(x0[jj] - x1[jj]));  // softmax class-1
        acc += prob * dist;
    }
#pragma unroll
    for (int off = 32; off > 0; off >>= 1) acc += __shfl_down(acc, off, 64);
    if (lane == 0) partials[b * HH + row] = acc;
}

// ---------------------------------------------------------------------------
// Pass 3 (unchanged): single wave. 8x float4 partial loads per lane, per-batch
// presence guard via 4 ballots over the 32 pack-block flags, double reduce.
// ---------------------------------------------------------------------------
__global__ __launch_bounds__(64) void finalize_kernel(
    const int* __restrict__ flags,
    const float* __restrict__ partials,
    float* __restrict__ out)
{
    int k = threadIdx.x;

    double presd[BB];
#pragma unroll
    for (int b = 0; b < BB; ++b) {
        int f = (k < 32) ? flags[b * 32 + k] : 0;
        presd[b] = (__ballot(f != 0) != 0ULL) ? 1.0 : 0.0;  // 'mask.sum()>0'
    }

    const float4* p4 = (const float4*)partials;
    double s = 0.0;
#pragma unroll
    for (int t = 0; t < 8; ++t) {
        int v4 = k + 64 * t;                 // float4 index 0..511
        float4 v = p4[v4];
        double gd = presd[v4 >> 7];          // batch = (4*v4)>>9
        s += gd * ((double)v.x + (double)v.y + (double)v.z + (double)v.w);
    }
#pragma unroll
    for (int off = 32; off > 0; off >>= 1) s += __shfl_down(s, off, 64);
    if (k == 0)
        out[0] = (float)(s * (1.0 / 2097152.0));   // mean over B*C*H*W
}

extern "C" void kernel_launch(void* const* d_in, const int* in_sizes, int n_in,
                              void* d_out, int out_size, void* d_ws, size_t ws_size,
                              hipStream_t stream) {
    const float* pred = (const float*)d_in[0];
    const int* target = (const int*)d_in[1];
    float* out = (float*)d_out;

    char* ws = (char*)d_ws;
    int* flags = (int*)(ws + 0);
    float* partials = (float*)(ws + 1024);
    unsigned int* cw = (unsigned int*)(ws + 32768);

    pack_kernel<<<128, 256, 0, stream>>>(target, cw, flags);
    rows_kernel<<<ROWS_BLOCKS, 512, 0, stream>>>(cw, pred, partials);
    finalize_kernel<<<1, 64, 0, stream>>>(flags, partials, out);
}